// Round 4
// baseline (187.554 us; speedup 1.0000x reference)
//
#include <hip/hip_runtime.h>
#include <stdint.h>

#define NE    8
#define NTOK  1024
#define NH    1024
#define NI    1024
#define N13   2048

#define PREP_BLOCKS 513
#define G1MAX       1248  // sum_e ceil(cnt/64) <= 39, * 32 ntiles
#define G2MAX       1248  // 39 * 16 ntiles * 2 ksplit

typedef __attribute__((ext_vector_type(8))) short short8;
typedef __attribute__((ext_vector_type(4))) float f32x4;
typedef unsigned short u16;
typedef unsigned int   u32;

__device__ __forceinline__ u16 f2bf(float x) {
    union { float f; u32 u; } v; v.f = x;
    return (u16)((v.u + 0x7fffu + ((v.u >> 16) & 1u)) >> 16);
}
__device__ __forceinline__ u32 pack2(float a, float b) {
    return (u32)f2bf(a) | ((u32)f2bf(b) << 16);
}
// packed RNE f32->bf16 pair: lo -> low half, hi -> high half
__device__ __forceinline__ u32 cvt_pk(float lo, float hi) {
    u32 r;
    asm("v_cvt_pk_bf16_f32 %0, %1, %2" : "=v"(r) : "v"(lo), "v"(hi));
    return r;
}
__device__ __forceinline__ void async_ld16(u16* lds, const u16* g) {
    __builtin_amdgcn_global_load_lds(
        (const __attribute__((address_space(1))) u32*)g,
        (__attribute__((address_space(3))) u32*)lds, 16, 0, 0);
}

// nt-fastest: panel (e,nt) readers sit at stride ntn (mult of 8) -> same XCD L2
__device__ __forceinline__ bool find_tile(
    const int* __restrict__ counts, int tile, int bm, int ntn,
    int& e_o, int& mt_o, int& nt_o, int& cnt_o, int& base_o)
{
    int base = 0;
    #pragma unroll
    for (int e = 0; e < NE; e++) {
        const int cnt = counts[e];
        const int mtiles = (cnt + bm - 1) / bm;
        const int tiles = mtiles * ntn;
        if (tile < tiles) {
            e_o = e; mt_o = tile / ntn; nt_o = tile - (tile / ntn) * ntn;
            cnt_o = cnt; base_o = base; return true;
        }
        tile -= tiles; base += cnt;
    }
    return false;
}

// counted-vmcnt sync: leave newest N vmem in flight across the barrier
#define SYNCV(N)                                                           \
    {                                                                      \
        asm volatile("s_waitcnt vmcnt(" #N ") lgkmcnt(0)" ::: "memory");   \
        __builtin_amdgcn_s_barrier();                                      \
        __builtin_amdgcn_sched_barrier(0);                                 \
    }

// ===========================================================================
// Prep: block 0 = routing (+ inverse map); blocks 1..512 = X -> bf16 (linear)
// ===========================================================================
__global__ __launch_bounds__(256) void prep_kernel(
    const float* __restrict__ X, const float* __restrict__ logits,
    int* __restrict__ counts, int* __restrict__ pair_tok,
    int* __restrict__ inv, float* __restrict__ tokw,
    u16* __restrict__ Xb)
{
    __shared__ int s_cnt[NE];
    __shared__ int s_base[NE];
    const int tid = threadIdx.x;
    const int b = blockIdx.x;

    if (b == 0) {
        if (tid < NE) s_cnt[tid] = 0;
        __syncthreads();
        int eA[4][2]; int slotA[4][2]; float wA[4][2];
        #pragma unroll
        for (int i = 0; i < 4; i++) {
            const int t = tid * 4 + i;
            float l[NE];
            #pragma unroll
            for (int e = 0; e < NE; e++) l[e] = logits[t * NE + e];
            int i0 = 0;
            #pragma unroll
            for (int e = 1; e < NE; e++) if (l[e] > l[i0]) i0 = e;
            int i1 = -1;
            #pragma unroll
            for (int e = 0; e < NE; e++) {
                if (e == i0) continue;
                if (i1 < 0 || l[e] > l[i1]) i1 = e;
            }
            const float e10 = __expf(l[i1] - l[i0]);
            const float invw = 1.0f / (1.0f + e10);
            eA[i][0] = i0; eA[i][1] = i1;
            wA[i][0] = invw; wA[i][1] = e10 * invw;
            slotA[i][0] = atomicAdd(&s_cnt[i0], 1);
            slotA[i][1] = atomicAdd(&s_cnt[i1], 1);
        }
        __syncthreads();
        if (tid == 0) {
            int acc = 0;
            #pragma unroll
            for (int e = 0; e < NE; e++) { s_base[e] = acc; acc += s_cnt[e]; }
        }
        __syncthreads();
        if (tid < NE) counts[tid] = s_cnt[tid];
        #pragma unroll
        for (int i = 0; i < 4; i++) {
            const int t = tid * 4 + i;
            #pragma unroll
            for (int k = 0; k < 2; k++) {
                const int p = s_base[eA[i][k]] + slotA[i][k];
                pair_tok[p] = t;
                inv[t * 2 + k] = p;
                tokw[t * 2 + k] = wA[i][k];
            }
        }
    } else {
        const int i = (b - 1) * 256 + tid;
        const float4* s = (const float4*)X;
        const float4 a = s[2 * i], c = s[2 * i + 1];
        uint4 o;
        o.x = pack2(a.x, a.y);
        o.y = pack2(a.z, a.w);
        o.z = pack2(c.x, c.y);
        o.w = pack2(c.z, c.w);
        *(uint4*)(Xb + (size_t)i * 8) = o;
    }
}

// ===========================================================================
// GEMM1: act = silu(X.Wg)*X.Wu   BM=64, 32 act cols (64 wcols), BK=32.
// S=3 LDS ring; A gload_lds 2 iters ahead; B fp32->reg 3 iters ahead,
// cvt_pk + conflict-free ds_write 1 iter ahead; SYNC vmcnt(3) steady.
// A LDS [64r][32k], slot s of row r holds k-chunk s^((r>>1)&3).
// B LDS [64n][40k-pad], slot s of row n holds k-chunk s^((n>>3)&3).
// ===========================================================================
__global__ __launch_bounds__(256, 4) void gemm1_kernel(
    const u16* __restrict__ Xb, const float* __restrict__ W13,
    const int* __restrict__ counts, const int* __restrict__ pair_tok,
    u16* __restrict__ act)
{
    int e, mt, nt, cnt, base;
    if (!find_tile(counts, blockIdx.x, 64, 32, e, mt, nt, cnt, base)) return;

    __shared__ __align__(16) u16 As[3][64 * 32];
    __shared__ __align__(16) u16 Bs[3][64 * 40];

    const int tid = threadIdx.x;
    const int ct  = nt * 32;

    // A staging: one gload_lds/iter; thread -> row tid>>2, slot tid&3
    const int csrc = (((tid & 3) ^ ((tid >> 3) & 3)) << 3);
    const int arow = mt * 64 + (tid >> 2);
    const int tok  = pair_tok[base + min(arow, cnt - 1)];
    const u16* ga  = Xb + (size_t)tok * NH + csrc;

    // B: coalesced fp32, n across lanes, k-pair = tid>>4
    const int n0 = (tid & 15) << 2;
    const int kp = tid >> 4;
    const int kc = kp >> 2;
    const int f0 = (n0 < 32) ? (ct + n0) : (NI + ct + n0 - 32);
    const float* gw = W13 + ((size_t)e * NH + 2 * kp) * N13 + f0;
    int wboff[4];
    #pragma unroll
    for (int jj = 0; jj < 4; jj++) {
        const int n = n0 + jj;
        wboff[jj] = n * 40 + ((kc ^ ((n >> 3) & 3)) << 3) + ((kp & 3) << 1);
    }

    const int lane = tid & 63, w = tid >> 6;
    const int quad = lane >> 4, lid = lane & 15;
    const int rw = w >> 1, cw = w & 1;
    int aoff[2];
    #pragma unroll
    for (int mi = 0; mi < 2; mi++) {
        const int r = rw * 32 + mi * 16 + lid;
        aoff[mi] = r * 32 + ((quad ^ ((r >> 1) & 3)) << 3);
    }
    int bgoff, buoff;
    { const int n = cw * 16 + lid;
      bgoff = n * 40 + ((quad ^ ((n >> 3) & 3)) << 3); }
    { const int n = 32 + cw * 16 + lid;
      buoff = n * 40 + ((quad ^ ((n >> 3) & 3)) << 3); }

    f32x4 accg[2] = {};
    f32x4 accu[2] = {};
    float4 bq[3][2];

#define ISSUEA1(S, K) async_ld16(&As[S][tid * 8], ga + (K));
#define LOADB1(RB, K)                                                      \
    { bq[RB][0] = *(const float4*)(gw + (size_t)(K) * N13);                \
      bq[RB][1] = *(const float4*)(gw + (size_t)(K) * N13 + N13); }
#define WRB1(S)                                                            \
    { _Pragma("unroll") for (int jj = 0; jj < 4; jj++) {                   \
        *(u32*)&Bs[S][wboff[jj]] =                                         \
            cvt_pk(((const float*)&bq[S][0])[jj],                          \
                   ((const float*)&bq[S][1])[jj]);                         \
    } }
#define COMP1(S)                                                           \
    {                                                                      \
        const short8 gv = *(const short8*)&Bs[S][bgoff];                   \
        const short8 uv = *(const short8*)&Bs[S][buoff];                   \
        __builtin_amdgcn_s_setprio(1);                                     \
        _Pragma("unroll") for (int mi = 0; mi < 2; mi++) {                 \
            const short8 av = *(const short8*)&As[S][aoff[mi]];            \
            accg[mi] = __builtin_amdgcn_mfma_f32_16x16x32_bf16(            \
                av, gv, accg[mi], 0, 0, 0);                                \
            accu[mi] = __builtin_amdgcn_mfma_f32_16x16x32_bf16(            \
                av, uv, accu[mi], 0, 0, 0);                                \
        }                                                                  \
        __builtin_amdgcn_s_setprio(0);                                     \
    }
#define G1_STEP(J, NV)                                                     \
    SYNCV(NV)                                                              \
    if ((J) + 2 < 32) { ISSUEA1((((J) + 2) % 3), (((J) + 2) * 32)) }       \
    if ((J) + 3 < 32) { LOADB1(((J) % 3), (((J) + 3) * 32)) }              \
    COMP1(((J) % 3))                                                       \
    if ((J) + 1 < 32) { WRB1((((J) + 1) % 3)) }

    // prologue: B(0),A(0),B(1),A(1),B(2) issued; vmcnt(6) forces B(0)
    LOADB1(0, 0)
    ISSUEA1(0, 0)
    LOADB1(1, 32)
    ISSUEA1(1, 32)
    LOADB1(2, 64)
    asm volatile("s_waitcnt vmcnt(6)" ::: "memory");
    WRB1(0)

    G1_STEP(0, 3)  G1_STEP(1, 3)  G1_STEP(2, 3)  G1_STEP(3, 3)
    G1_STEP(4, 3)  G1_STEP(5, 3)  G1_STEP(6, 3)  G1_STEP(7, 3)
    G1_STEP(8, 3)  G1_STEP(9, 3)  G1_STEP(10, 3) G1_STEP(11, 3)
    G1_STEP(12, 3) G1_STEP(13, 3) G1_STEP(14, 3) G1_STEP(15, 3)
    G1_STEP(16, 3) G1_STEP(17, 3) G1_STEP(18, 3) G1_STEP(19, 3)
    G1_STEP(20, 3) G1_STEP(21, 3) G1_STEP(22, 3) G1_STEP(23, 3)
    G1_STEP(24, 3) G1_STEP(25, 3) G1_STEP(26, 3) G1_STEP(27, 3)
    G1_STEP(28, 3) G1_STEP(29, 3) G1_STEP(30, 1) G1_STEP(31, 0)

    const int col = ct + cw * 16 + lid;
    #pragma unroll
    for (int mi = 0; mi < 2; mi++) {
        #pragma unroll
        for (int r = 0; r < 4; r++) {
            const int row = mt * 64 + rw * 32 + mi * 16 + quad * 4 + r;
            if (row < cnt) {
                const float g = accg[mi][r], u = accu[mi][r];
                act[(size_t)(base + row) * NI + col] =
                    f2bf(g / (1.0f + __expf(-g)) * u);
            }
        }
    }
#undef ISSUEA1
#undef LOADB1
#undef WRB1
#undef COMP1
#undef G1_STEP
}

// ===========================================================================
// GEMM2: down[kh][p] = act[p][half] . W2[e][half]   BM=64 x BN=64, BK=32,
// K-split 2, same S=3 ring pipeline (NK=16).
// ===========================================================================
__global__ __launch_bounds__(256, 4) void gemm2_kernel(
    const u16* __restrict__ act, const float* __restrict__ W2,
    const int* __restrict__ counts,
    float* __restrict__ down0, float* __restrict__ down1)
{
    int e, mt, ntq, cnt, base;
    if (!find_tile(counts, blockIdx.x, 64, 32, e, mt, ntq, cnt, base)) return;
    const int kh = ntq & 1;
    const int nt = ntq >> 1;
    const int ct = nt * 64;
    const int kbase = kh * 512;
    float* __restrict__ dwn = kh ? down1 : down0;

    __shared__ __align__(16) u16 As[3][64 * 32];
    __shared__ __align__(16) u16 Bs[3][64 * 40];

    const int tid = threadIdx.x;

    const int csrc = (((tid & 3) ^ ((tid >> 3) & 3)) << 3);
    const int arow = mt * 64 + (tid >> 2);
    const int p    = base + min(arow, cnt - 1);
    const u16* ga  = act + (size_t)p * NI + kbase + csrc;

    const int n0 = (tid & 15) << 2;
    const int kp = tid >> 4;
    const int kc = kp >> 2;
    const float* gw = W2 + ((size_t)e * NI + kbase + 2 * kp) * NH + ct + n0;
    int wboff[4];
    #pragma unroll
    for (int jj = 0; jj < 4; jj++) {
        const int n = n0 + jj;
        wboff[jj] = n * 40 + ((kc ^ ((n >> 3) & 3)) << 3) + ((kp & 3) << 1);
    }

    const int lane = tid & 63, w = tid >> 6;
    const int quad = lane >> 4, lid = lane & 15;
    const int rw = w >> 1, cw = w & 1;
    int aoff[2], boff[2];
    #pragma unroll
    for (int mi = 0; mi < 2; mi++) {
        const int r = rw * 32 + mi * 16 + lid;
        aoff[mi] = r * 32 + ((quad ^ ((r >> 1) & 3)) << 3);
    }
    #pragma unroll
    for (int nj = 0; nj < 2; nj++) {
        const int n = cw * 32 + nj * 16 + lid;
        boff[nj] = n * 40 + ((quad ^ ((n >> 3) & 3)) << 3);
    }

    f32x4 acc[2][2] = {};
    float4 bq[3][2];

#define ISSUEA2(S, K) async_ld16(&As[S][tid * 8], ga + (K));
#define LOADB2(RB, K)                                                      \
    { bq[RB][0] = *(const float4*)(gw + (size_t)(K) * NH);                 \
      bq[RB][1] = *(const float4*)(gw + (size_t)(K) * NH + NH); }
#define WRB2(S)                                                            \
    { _Pragma("unroll") for (int jj = 0; jj < 4; jj++) {                   \
        *(u32*)&Bs[S][wboff[jj]] =                                         \
            cvt_pk(((const float*)&bq[S][0])[jj],                          \
                   ((const float*)&bq[S][1])[jj]);                         \
    } }
#define COMP2(S)                                                           \
    {                                                                      \
        const short8 bv0 = *(const short8*)&Bs[S][boff[0]];                \
        const short8 bv1 = *(const short8*)&Bs[S][boff[1]];                \
        __builtin_amdgcn_s_setprio(1);                                     \
        _Pragma("unroll") for (int mi = 0; mi < 2; mi++) {                 \
            const short8 av = *(const short8*)&As[S][aoff[mi]];            \
            acc[mi][0] = __builtin_amdgcn_mfma_f32_16x16x32_bf16(          \
                av, bv0, acc[mi][0], 0, 0, 0);                             \
            acc[mi][1] = __builtin_amdgcn_mfma_f32_16x16x32_bf16(          \
                av, bv1, acc[mi][1], 0, 0, 0);                             \
        }                                                                  \
        __builtin_amdgcn_s_setprio(0);                                     \
    }
#define G2_STEP(J, NV)                                                     \
    SYNCV(NV)                                                              \
    if ((J) + 2 < 16) { ISSUEA2((((J) + 2) % 3), (((J) + 2) * 32)) }       \
    if ((J) + 3 < 16) { LOADB2(((J) % 3), (((J) + 3) * 32)) }              \
    COMP2(((J) % 3))                                                       \
    if ((J) + 1 < 16) { WRB2((((J) + 1) % 3)) }

    LOADB2(0, 0)
    ISSUEA2(0, 0)
    LOADB2(1, 32)
    ISSUEA2(1, 32)
    LOADB2(2, 64)
    asm volatile("s_waitcnt vmcnt(6)" ::: "memory");
    WRB2(0)

    G2_STEP(0, 3)  G2_STEP(1, 3)  G2_STEP(2, 3)  G2_STEP(3, 3)
    G2_STEP(4, 3)  G2_STEP(5, 3)  G2_STEP(6, 3)  G2_STEP(7, 3)
    G2_STEP(8, 3)  G2_STEP(9, 3)  G2_STEP(10, 3) G2_STEP(11, 3)
    G2_STEP(12, 3) G2_STEP(13, 3) G2_STEP(14, 1) G2_STEP(15, 0)

    #pragma unroll
    for (int mi = 0; mi < 2; mi++) {
        #pragma unroll
        for (int r = 0; r < 4; r++) {
            const int row = mt * 64 + rw * 32 + mi * 16 + quad * 4 + r;
            if (row < cnt) {
                #pragma unroll
                for (int nj = 0; nj < 2; nj++) {
                    dwn[(size_t)(base + row) * NH + ct + cw * 32 + nj * 16 + lid] =
                        acc[mi][nj][r];
                }
            }
        }
    }
#undef ISSUEA2
#undef LOADB2
#undef WRB2
#undef COMP2
#undef G2_STEP
}

// ===========================================================================
// Combine: out[t] = w0*(d0[p0]+d1[p0]) + w1*(d0[p1]+d1[p1])
// ===========================================================================
__global__ __launch_bounds__(256) void combine_kernel(
    const float* __restrict__ down0, const float* __restrict__ down1,
    const int* __restrict__ inv, const float* __restrict__ tokw,
    float* __restrict__ out)
{
    const int t = blockIdx.x;
    const int p0 = inv[2 * t], p1 = inv[2 * t + 1];
    const float w0 = tokw[2 * t], w1 = tokw[2 * t + 1];
    const int i = threadIdx.x * 4;
    const float4 a0 = *(const float4*)(down0 + (size_t)p0 * NH + i);
    const float4 a1 = *(const float4*)(down1 + (size_t)p0 * NH + i);
    const float4 b0 = *(const float4*)(down0 + (size_t)p1 * NH + i);
    const float4 b1 = *(const float4*)(down1 + (size_t)p1 * NH + i);
    float4 o;
    o.x = w0 * (a0.x + a1.x) + w1 * (b0.x + b1.x);
    o.y = w0 * (a0.y + a1.y) + w1 * (b0.y + b1.y);
    o.z = w0 * (a0.z + a1.z) + w1 * (b0.z + b1.z);
    o.w = w0 * (a0.w + a1.w) + w1 * (b0.w + b1.w);
    *(float4*)(out + (size_t)t * NH + i) = o;
}

// ===========================================================================
extern "C" void kernel_launch(void* const* d_in, const int* in_sizes, int n_in,
                              void* d_out, int out_size, void* d_ws, size_t ws_size,
                              hipStream_t stream)
{
    const float* X      = (const float*)d_in[0];
    const float* logits = (const float*)d_in[1];
    const float* W13    = (const float*)d_in[2];
    const float* W2     = (const float*)d_in[3];
    float* out = (float*)d_out;

    char* ws = (char*)d_ws;
    int*   counts   = (int*)(ws + 0);
    int*   pair_tok = (int*)(ws + 1024);
    int*   inv      = (int*)(ws + 16384);
    float* tokw     = (float*)(ws + 32768);
    u16*   Xb       = (u16*)(ws + 65536);                      // 2 MiB [T][H] bf16
    u16*   act      = (u16*)(ws + (size_t)4  * 1024 * 1024);   // 4 MiB [P][I] bf16
    float* down0    = (float*)(ws + (size_t)8  * 1024 * 1024); // 8 MiB
    float* down1    = (float*)(ws + (size_t)16 * 1024 * 1024); // 8 MiB

    prep_kernel<<<PREP_BLOCKS, 256, 0, stream>>>(
        X, logits, counts, pair_tok, inv, tokw, Xb);
    gemm1_kernel<<<G1MAX, 256, 0, stream>>>(Xb, W13, counts, pair_tok, act);
    gemm2_kernel<<<G2MAX, 256, 0, stream>>>(act, W2, counts, down0, down1);
    combine_kernel<<<NTOK, 256, 0, stream>>>(down0, down1, inv, tokw, out);
}

// Round 6
// 171.724 us; speedup vs baseline: 1.0922x; 1.0922x over previous
//
#include <hip/hip_runtime.h>
#include <stdint.h>

#define NE    8
#define NTOK  1024
#define NH    1024
#define NI    1024
#define N13   2048

#define PREP_BLOCKS 6657   // 1 routing + 512 Xcvt + 4096 W13t + 2048 W2t tiles
#define G1MAX       768
#define G2MAX       768

typedef __attribute__((ext_vector_type(8))) short short8;
typedef __attribute__((ext_vector_type(4))) float f32x4;
typedef unsigned short u16;
typedef unsigned int   u32;

__device__ __forceinline__ u16 f2bf(float x) {
    union { float f; u32 u; } v; v.f = x;
    return (u16)((v.u + 0x7fffu + ((v.u >> 16) & 1u)) >> 16);
}
// packed RNE f32->bf16: lo -> low half, hi -> high half
__device__ __forceinline__ u32 cvt_pk(float lo, float hi) {
    u32 r;
    asm("v_cvt_pk_bf16_f32 %0, %1, %2" : "=v"(r) : "v"(lo), "v"(hi));
    return r;
}
__device__ __forceinline__ void async_ld16(u16* lds, const u16* g) {
    __builtin_amdgcn_global_load_lds(
        (const __attribute__((address_space(1))) u32*)g,
        (__attribute__((address_space(3))) u32*)lds, 16, 0, 0);
}

// nt-fastest: panel-sharing blocks sit at stride ntn (mult of 8) -> same XCD L2
__device__ __forceinline__ bool find_tile(
    const int* __restrict__ counts, int tile, int bm, int ntn,
    int& e_o, int& mt_o, int& nt_o, int& cnt_o, int& base_o)
{
    int base = 0;
    #pragma unroll
    for (int e = 0; e < NE; e++) {
        const int cnt = counts[e];
        const int mtiles = (cnt + bm - 1) / bm;
        const int tiles = mtiles * ntn;
        if (tile < tiles) {
            e_o = e; mt_o = tile / ntn; nt_o = tile - (tile / ntn) * ntn;
            cnt_o = cnt; base_o = base; return true;
        }
        tile -= tiles; base += cnt;
    }
    return false;
}

// counted-vmcnt barrier: wave waits for ITS stage-J loads BEFORE the barrier,
// so after the barrier all waves' stage-J writes are visible.
#define SYNCV(N)                                                           \
    {                                                                      \
        asm volatile("s_waitcnt vmcnt(" #N ") lgkmcnt(0)" ::: "memory");   \
        __builtin_amdgcn_s_barrier();                                      \
        __builtin_amdgcn_sched_barrier(0);                                 \
    }

// ===========================================================================
// Prep: b0 = routing; b1..512 = X->bf16 (linear); b513.. = W transpose+cvt
// W13t [E][N13][NH] bf16, W2t [E][NH][NI] bf16  (R0-verified transpose code)
// ===========================================================================
__global__ __launch_bounds__(256) void prep_kernel(
    const float* __restrict__ X, const float* __restrict__ logits,
    const float* __restrict__ W13, const float* __restrict__ W2,
    int* __restrict__ counts, int* __restrict__ pair_tok,
    int* __restrict__ inv, float* __restrict__ tokw,
    u16* __restrict__ Xb, u16* __restrict__ W13t, u16* __restrict__ W2t)
{
    __shared__ __align__(16) float Ts[64][65];
    const int tid = threadIdx.x;
    const int b = blockIdx.x;

    if (b == 0) {
        int* s_cnt  = (int*)&Ts[0][0];
        int* s_base = s_cnt + NE;
        if (tid < NE) s_cnt[tid] = 0;
        __syncthreads();
        int eA[4][2]; int slotA[4][2]; float wA[4][2];
        #pragma unroll
        for (int i = 0; i < 4; i++) {
            const int t = tid * 4 + i;
            float l[NE];
            #pragma unroll
            for (int e = 0; e < NE; e++) l[e] = logits[t * NE + e];
            int i0 = 0;
            #pragma unroll
            for (int e = 1; e < NE; e++) if (l[e] > l[i0]) i0 = e;
            int i1 = -1;
            #pragma unroll
            for (int e = 0; e < NE; e++) {
                if (e == i0) continue;
                if (i1 < 0 || l[e] > l[i1]) i1 = e;
            }
            const float e10 = __expf(l[i1] - l[i0]);
            const float invw = 1.0f / (1.0f + e10);
            eA[i][0] = i0; eA[i][1] = i1;
            wA[i][0] = invw; wA[i][1] = e10 * invw;
            slotA[i][0] = atomicAdd(&s_cnt[i0], 1);
            slotA[i][1] = atomicAdd(&s_cnt[i1], 1);
        }
        __syncthreads();
        if (tid == 0) {
            int acc = 0;
            #pragma unroll
            for (int e = 0; e < NE; e++) { s_base[e] = acc; acc += s_cnt[e]; }
        }
        __syncthreads();
        if (tid < NE) counts[tid] = s_cnt[tid];
        #pragma unroll
        for (int i = 0; i < 4; i++) {
            const int t = tid * 4 + i;
            #pragma unroll
            for (int k = 0; k < 2; k++) {
                const int p = s_base[eA[i][k]] + slotA[i][k];
                pair_tok[p] = t;
                inv[t * 2 + k] = p;
                tokw[t * 2 + k] = wA[i][k];
            }
        }
    } else if (b <= 512) {
        const int i = (b - 1) * 256 + tid;
        const float4* s = (const float4*)X;
        const float4 a = s[2 * i], c = s[2 * i + 1];
        uint4 o;
        o.x = cvt_pk(a.x, a.y);
        o.y = cvt_pk(a.z, a.w);
        o.z = cvt_pk(c.x, c.y);
        o.w = cvt_pk(c.z, c.w);
        *(uint4*)(Xb + (size_t)i * 8) = o;
    } else {
        const int wb = b - 513;
        const float* src; u16* dst; int K, N, tb;
        if (wb < 4096) { src = W13; dst = W13t; K = NH; N = N13; tb = wb; }
        else           { src = W2;  dst = W2t;  K = NI; N = NH;  tb = wb - 4096; }
        const int ktiles = K >> 6, ntiles = N >> 6;
        const int tpe = ktiles * ntiles;
        const int e = tb / tpe;
        const int rem = tb - e * tpe;
        const int kt = rem / ntiles, ntl = rem - (rem / ntiles) * ntiles;
        const float* sb = src + ((size_t)e * K + (size_t)kt * 64) * N + ntl * 64;
        #pragma unroll
        for (int i = 0; i < 4; i++) {
            const int idx = tid + i * 256;
            const int r = idx >> 4, c = (idx & 15) << 2;
            const float4 v = *(const float4*)(sb + (size_t)r * N + c);
            Ts[r][c + 0] = v.x; Ts[r][c + 1] = v.y;
            Ts[r][c + 2] = v.z; Ts[r][c + 3] = v.w;
        }
        __syncthreads();
        u16* db = dst + ((size_t)e * N + (size_t)ntl * 64) * K + kt * 64;
        #pragma unroll
        for (int i = 0; i < 2; i++) {
            const int u = tid + i * 256;
            const int n = u >> 3, k8 = (u & 7) << 3;
            uint4 o;
            o.x = cvt_pk(Ts[k8 + 0][n], Ts[k8 + 1][n]);
            o.y = cvt_pk(Ts[k8 + 2][n], Ts[k8 + 3][n]);
            o.z = cvt_pk(Ts[k8 + 4][n], Ts[k8 + 5][n]);
            o.w = cvt_pk(Ts[k8 + 6][n], Ts[k8 + 7][n]);
            *(uint4*)(db + (size_t)n * K + k8) = o;
        }
    }
}

// ===========================================================================
// GEMM1: act = silu(X.Wg)*X.Wu   BM=128, 64 wcols (32 act), BK=32, NK=32.
// Pure global_load_lds staging (bf16 both operands), S=4 LDS ring.
// Step order: SYNCV(6) -> STAGE(J+3) -> COMP(J).  Stage J+3 targets buf
// (J-1)&3, whose readers all finished BEFORE barrier(J) -> race-free; the
// wait (before the barrier) retires stage J so COMP(J) sees all waves' data.
// XOR pre-swizzle chunk ^= (row>>1)&3 -> every b128 read phase 2-way (free).
// ===========================================================================
__global__ __launch_bounds__(256, 3) void gemm1_kernel(
    const u16* __restrict__ Xb, const u16* __restrict__ W13t,
    const int* __restrict__ counts, const int* __restrict__ pair_tok,
    u16* __restrict__ act)
{
    int e, mt, nt, cnt, base;
    if (!find_tile(counts, blockIdx.x, 128, 32, e, mt, nt, cnt, base)) return;

    __shared__ __align__(16) u16 As[4][128 * 32];
    __shared__ __align__(16) u16 Bs[4][64 * 32];

    const int tid = threadIdx.x;
    const int ct  = nt * 32;

    // chunk swizzle: dest chunk c0 of row r holds source chunk c0^((r>>1)&3)
    const int sc = (((tid & 3) ^ ((tid >> 3) & 3)) << 3);  // u16 units
    const int rr = tid >> 2;                               // 0..63
    const int tok0 = pair_tok[base + min(mt * 128 + rr,      cnt - 1)];
    const int tok1 = pair_tok[base + min(mt * 128 + 64 + rr, cnt - 1)];
    const u16* ga0 = Xb + (size_t)tok0 * NH + sc;
    const u16* ga1 = Xb + (size_t)tok1 * NH + sc;
    const int wcol = (rr < 32) ? (ct + rr) : (NI + ct + rr - 32);
    const u16* gb  = W13t + ((size_t)e * N13 + wcol) * NH + sc;

    const int lane = tid & 63, w = tid >> 6;
    const int quad = lane >> 4, lid = lane & 15;
    const int rw = w >> 1, cw = w & 1;
    int aoff[4];
    #pragma unroll
    for (int mi = 0; mi < 4; mi++) {
        const int row = rw * 64 + mi * 16 + lid;
        aoff[mi] = row * 32 + ((quad ^ ((row >> 1) & 3)) << 3);
    }
    int bgoff, buoff;
    { const int n = cw * 16 + lid;
      bgoff = n * 32 + ((quad ^ ((n >> 1) & 3)) << 3); }
    { const int n = 32 + cw * 16 + lid;
      buoff = n * 32 + ((quad ^ ((n >> 1) & 3)) << 3); }

    f32x4 accg[4] = {};
    f32x4 accu[4] = {};

#define STAGE1(S, K)                                                       \
    {                                                                      \
        async_ld16(&As[S][tid * 8],         ga0 + (K));                    \
        async_ld16(&As[S][(256 + tid) * 8], ga1 + (K));                    \
        async_ld16(&Bs[S][tid * 8],         gb  + (K));                    \
    }
#define COMP1(S)                                                           \
    {                                                                      \
        const short8 gv = *(const short8*)&Bs[S][bgoff];                   \
        const short8 uv = *(const short8*)&Bs[S][buoff];                   \
        __builtin_amdgcn_s_setprio(1);                                     \
        _Pragma("unroll") for (int mi = 0; mi < 4; mi++) {                 \
            const short8 av = *(const short8*)&As[S][aoff[mi]];            \
            accg[mi] = __builtin_amdgcn_mfma_f32_16x16x32_bf16(            \
                av, gv, accg[mi], 0, 0, 0);                                \
            accu[mi] = __builtin_amdgcn_mfma_f32_16x16x32_bf16(            \
                av, uv, accu[mi], 0, 0, 0);                                \
        }                                                                  \
        __builtin_amdgcn_s_setprio(0);                                     \
    }
#define STEP1(J, NV)                                                       \
    SYNCV(NV)                                                              \
    if ((J) + 3 < 32) { STAGE1((((J) + 3) & 3), (((J) + 3) * 32)) }        \
    COMP1(((J) & 3))

    STAGE1(0, 0)
    STAGE1(1, 32)
    STAGE1(2, 64)

    STEP1(0, 6)  STEP1(1, 6)  STEP1(2, 6)  STEP1(3, 6)
    STEP1(4, 6)  STEP1(5, 6)  STEP1(6, 6)  STEP1(7, 6)
    STEP1(8, 6)  STEP1(9, 6)  STEP1(10, 6) STEP1(11, 6)
    STEP1(12, 6) STEP1(13, 6) STEP1(14, 6) STEP1(15, 6)
    STEP1(16, 6) STEP1(17, 6) STEP1(18, 6) STEP1(19, 6)
    STEP1(20, 6) STEP1(21, 6) STEP1(22, 6) STEP1(23, 6)
    STEP1(24, 6) STEP1(25, 6) STEP1(26, 6) STEP1(27, 6)
    STEP1(28, 6) STEP1(29, 6) STEP1(30, 3) STEP1(31, 0)

    const int col = ct + cw * 16 + lid;
    #pragma unroll
    for (int mi = 0; mi < 4; mi++) {
        #pragma unroll
        for (int r = 0; r < 4; r++) {
            const int row = mt * 128 + rw * 64 + mi * 16 + quad * 4 + r;
            if (row < cnt) {
                const float g = accg[mi][r], u = accu[mi][r];
                act[(size_t)(base + row) * NI + col] =
                    f2bf(g / (1.0f + __expf(-g)) * u);
            }
        }
    }
#undef STAGE1
#undef COMP1
#undef STEP1
}

// ===========================================================================
// GEMM2: down[kh][p] = act[p][half] . W2[e][half]   BM=128 x BN=64, BK=32,
// K-split 2 (NK=16), same race-free S=4 counted-vmcnt pipeline.
// ===========================================================================
__global__ __launch_bounds__(256, 3) void gemm2_kernel(
    const u16* __restrict__ act, const u16* __restrict__ W2t,
    const int* __restrict__ counts,
    float* __restrict__ down0, float* __restrict__ down1)
{
    int e, mt, ntq, cnt, base;
    if (!find_tile(counts, blockIdx.x, 128, 32, e, mt, ntq, cnt, base)) return;
    const int kh = ntq & 1;
    const int nt = ntq >> 1;
    const int ct = nt * 64;
    const int kbase = kh * 512;
    float* __restrict__ dwn = kh ? down1 : down0;

    __shared__ __align__(16) u16 As[4][128 * 32];
    __shared__ __align__(16) u16 Bs[4][64 * 32];

    const int tid = threadIdx.x;

    const int sc = (((tid & 3) ^ ((tid >> 3) & 3)) << 3);
    const int rr = tid >> 2;
    const int p0 = base + min(mt * 128 + rr,      cnt - 1);
    const int p1 = base + min(mt * 128 + 64 + rr, cnt - 1);
    const u16* ga0 = act + (size_t)p0 * NI + kbase + sc;
    const u16* ga1 = act + (size_t)p1 * NI + kbase + sc;
    const u16* gb  = W2t + ((size_t)e * NH + ct + rr) * NI + kbase + sc;

    const int lane = tid & 63, w = tid >> 6;
    const int quad = lane >> 4, lid = lane & 15;
    const int rw = w >> 1, cw = w & 1;
    int aoff[4], boff[2];
    #pragma unroll
    for (int mi = 0; mi < 4; mi++) {
        const int row = rw * 64 + mi * 16 + lid;
        aoff[mi] = row * 32 + ((quad ^ ((row >> 1) & 3)) << 3);
    }
    #pragma unroll
    for (int nj = 0; nj < 2; nj++) {
        const int n = cw * 32 + nj * 16 + lid;
        boff[nj] = n * 32 + ((quad ^ ((n >> 1) & 3)) << 3);
    }

    f32x4 acc[4][2] = {};

#define STAGE2(S, K)                                                       \
    {                                                                      \
        async_ld16(&As[S][tid * 8],         ga0 + (K));                    \
        async_ld16(&As[S][(256 + tid) * 8], ga1 + (K));                    \
        async_ld16(&Bs[S][tid * 8],         gb  + (K));                    \
    }
#define COMP2(S)                                                           \
    {                                                                      \
        const short8 bv0 = *(const short8*)&Bs[S][boff[0]];                \
        const short8 bv1 = *(const short8*)&Bs[S][boff[1]];                \
        __builtin_amdgcn_s_setprio(1);                                     \
        _Pragma("unroll") for (int mi = 0; mi < 4; mi++) {                 \
            const short8 av = *(const short8*)&As[S][aoff[mi]];            \
            acc[mi][0] = __builtin_amdgcn_mfma_f32_16x16x32_bf16(          \
                av, bv0, acc[mi][0], 0, 0, 0);                             \
            acc[mi][1] = __builtin_amdgcn_mfma_f32_16x16x32_bf16(          \
                av, bv1, acc[mi][1], 0, 0, 0);                             \
        }                                                                  \
        __builtin_amdgcn_s_setprio(0);                                     \
    }
#define STEP2(J, NV)                                                       \
    SYNCV(NV)                                                              \
    if ((J) + 3 < 16) { STAGE2((((J) + 3) & 3), (((J) + 3) * 32)) }        \
    COMP2(((J) & 3))

    STAGE2(0, 0)
    STAGE2(1, 32)
    STAGE2(2, 64)

    STEP2(0, 6)  STEP2(1, 6)  STEP2(2, 6)  STEP2(3, 6)
    STEP2(4, 6)  STEP2(5, 6)  STEP2(6, 6)  STEP2(7, 6)
    STEP2(8, 6)  STEP2(9, 6)  STEP2(10, 6) STEP2(11, 6)
    STEP2(12, 6) STEP2(13, 6) STEP2(14, 3) STEP2(15, 0)

    #pragma unroll
    for (int mi = 0; mi < 4; mi++) {
        #pragma unroll
        for (int r = 0; r < 4; r++) {
            const int row = mt * 128 + rw * 64 + mi * 16 + quad * 4 + r;
            if (row < cnt) {
                #pragma unroll
                for (int nj = 0; nj < 2; nj++) {
                    dwn[(size_t)(base + row) * NH + ct + cw * 32 + nj * 16 + lid] =
                        acc[mi][nj][r];
                }
            }
        }
    }
#undef STAGE2
#undef COMP2
#undef STEP2
}

// ===========================================================================
// Combine: out[t] = w0*(d0[p0]+d1[p0]) + w1*(d0[p1]+d1[p1])
// ===========================================================================
__global__ __launch_bounds__(256) void combine_kernel(
    const float* __restrict__ down0, const float* __restrict__ down1,
    const int* __restrict__ inv, const float* __restrict__ tokw,
    float* __restrict__ out)
{
    const int t = blockIdx.x;
    const int p0 = inv[2 * t], p1 = inv[2 * t + 1];
    const float w0 = tokw[2 * t], w1 = tokw[2 * t + 1];
    const int i = threadIdx.x * 4;
    const float4 a0 = *(const float4*)(down0 + (size_t)p0 * NH + i);
    const float4 a1 = *(const float4*)(down1 + (size_t)p0 * NH + i);
    const float4 b0 = *(const float4*)(down0 + (size_t)p1 * NH + i);
    const float4 b1 = *(const float4*)(down1 + (size_t)p1 * NH + i);
    float4 o;
    o.x = w0 * (a0.x + a1.x) + w1 * (b0.x + b1.x);
    o.y = w0 * (a0.y + a1.y) + w1 * (b0.y + b1.y);
    o.z = w0 * (a0.z + a1.z) + w1 * (b0.z + b1.z);
    o.w = w0 * (a0.w + a1.w) + w1 * (b0.w + b1.w);
    *(float4*)(out + (size_t)t * NH + i) = o;
}

// ===========================================================================
extern "C" void kernel_launch(void* const* d_in, const int* in_sizes, int n_in,
                              void* d_out, int out_size, void* d_ws, size_t ws_size,
                              hipStream_t stream)
{
    const float* X      = (const float*)d_in[0];
    const float* logits = (const float*)d_in[1];
    const float* W13    = (const float*)d_in[2];
    const float* W2     = (const float*)d_in[3];
    float* out = (float*)d_out;

    char* ws = (char*)d_ws;
    int*   counts   = (int*)(ws + 0);
    int*   pair_tok = (int*)(ws + 1024);
    int*   inv      = (int*)(ws + 16384);
    float* tokw     = (float*)(ws + 32768);
    u16*   Xb       = (u16*)(ws + 65536);                       // 2 MiB [T][H]
    u16*   act      = (u16*)(ws + (size_t)4  * 1024 * 1024);    // 4 MiB [P][I]
    float* down0    = (float*)(ws + (size_t)8  * 1024 * 1024);  // 8 MiB
    float* down1    = (float*)(ws + (size_t)16 * 1024 * 1024);  // 8 MiB
    u16*   W13t     = (u16*)(ws + (size_t)24 * 1024 * 1024);    // 32 MiB [E][2I][H]
    u16*   W2t      = (u16*)(ws + (size_t)56 * 1024 * 1024);    // 16 MiB [E][H][I]

    prep_kernel<<<PREP_BLOCKS, 256, 0, stream>>>(
        X, logits, W13, W2, counts, pair_tok, inv, tokw, Xb, W13t, W2t);
    gemm1_kernel<<<G1MAX, 256, 0, stream>>>(Xb, W13t, counts, pair_tok, act);
    gemm2_kernel<<<G2MAX, 256, 0, stream>>>(act, W2t, counts, down0, down1);
    combine_kernel<<<NTOK, 256, 0, stream>>>(down0, down1, inv, tokw, out);
}